// Round 5
// baseline (985.391 us; speedup 1.0000x reference)
//
#include <hip/hip_runtime.h>

#define NEG_INF -9e15f
#define ALPHA 0.2f

// Wave-per-row + per-wave software pipeline. Each 64-lane wave owns a row
// stream; row n+1's global loads are issued right after row n's products are
// staged to LDS, so phases 2-4 of row n hide the prefetch latency. No
// __syncthreads anywhere -> no vmcnt drain; same-wave DS ops are in-order.
// Phase 4 reads a pre-packed W4[jj][d][4] table (dwordx4, coalesced).
constexpr int K = 32, D = 100, KD = K * D;     // 3200 floats, 800 float4
constexpr int NBLK = 768;                      // 3 blocks/CU (LDS-bound)
constexpr int WPB = 4;
constexpr int NSTREAM = NBLK * WPB;            // 3072 row streams

// W4[jj*400 + d*4 + c] = Wout[d][4*jj+c]  (jj<25, d<100, c<4) -> 40 KB
__global__ __launch_bounds__(256) void pack_wout(
    const float* __restrict__ W, float* __restrict__ W4)
{
    int idx = blockIdx.x * 256 + threadIdx.x;
    if (idx < D * D) {
        int jj = idx / 400;
        int r  = idx - jj * 400;
        int d  = r >> 2;
        int c  = r & 3;
        W4[idx] = W[d * D + 4 * jj + c];
    }
}

__global__ __launch_bounds__(256, 3) void gat_wave_pipe(
    const float* __restrict__ item,   // [N, D]
    const float* __restrict__ ent,    // [N, K, D]
    const float* __restrict__ wr,     // [N, K, D]
    const int*   __restrict__ adj,    // [N, K]
    const float* __restrict__ W4,     // packed Wout in ws (40 KB)
    const float* __restrict__ bout,   // [D]
    float* __restrict__ out,          // [N, D]
    int N)
{
    __shared__ float4 sWe4[WPB * (KD / 4)];   // 51200 B, per-wave regions

    const int t   = threadIdx.x;
    const int wid = t >> 6;
    const int l   = t & 63;
    const int k   = l & 31;          // k-row this lane reduces in ksum
    const int h   = l >> 5;          // half of the k-row
    const bool bl = (l < 36);
    const int lb  = bl ? l : 35;

    float4* we4 = sWe4 + wid * (KD / 4);
    const float* we = reinterpret_cast<const float*>(we4);
    const float4* W4v = reinterpret_cast<const float4*>(W4);

    const float bouta = bout[l];
    const float boutb = bout[64 + lb];

    int n = blockIdx.x * WPB + wid;

    float4 a[12], b[12], at, bt;
    int   adjv; float itma, itmb;

#define LOADROW(NN, ADJ, ITA, ITB) do {                                        \
        const float4* e4_ = reinterpret_cast<const float4*>(ent + (size_t)(NN) * KD); \
        const float4* w4_ = reinterpret_cast<const float4*>(wr  + (size_t)(NN) * KD); \
        _Pragma("unroll")                                                      \
        for (int j = 0; j < 12; ++j) { a[j] = e4_[l + 64 * j]; b[j] = w4_[l + 64 * j]; } \
        if (l < 32) { at = e4_[768 + l]; bt = w4_[768 + l]; }                  \
        ADJ = adj[(size_t)(NN) * K + k];                                       \
        ITA = item[(size_t)(NN) * D + l];                                      \
        ITB = item[(size_t)(NN) * D + 64 + lb];                                \
    } while (0)

    LOADROW(n, adjv, itma, itmb);

    for (;;) {
        // ---- phase 1: products -> per-wave LDS (consumes a/b) ----
        #pragma unroll
        for (int j = 0; j < 12; ++j) {
            float4 p;
            p.x = a[j].x * b[j].x; p.y = a[j].y * b[j].y;
            p.z = a[j].z * b[j].z; p.w = a[j].w * b[j].w;
            we4[l + 64 * j] = p;
        }
        if (l < 32) {
            float4 p;
            p.x = at.x * bt.x; p.y = at.y * bt.y;
            p.z = at.z * bt.z; p.w = at.w * bt.w;
            we4[768 + l] = p;
        }

        // ---- issue next row's loads NOW; phases 2-4 hide the latency ----
        const int n2 = n + NSTREAM;
        const bool more = (n2 < N);
        int nadj = 0; float nitma = 0.f, nitmb = 0.f;
        if (more) LOADROW(n2, nadj, nitma, nitmb);

        // ---- ksum: lane (k,h) reads its half of k-row from LDS ----
        float s = 0.f;
        {
            const float4* base = we4 + k * 25 + (h ? 13 : 0);
            #pragma unroll
            for (int j = 0; j < 12; ++j) {
                float4 q = base[j];
                s += (q.x + q.y) + (q.z + q.w);
            }
            if (h == 0) {
                float4 q = base[12];
                s += (q.x + q.y) + (q.z + q.w);
            }
        }
        s += __shfl_xor(s, 32);

        // ---- softmax over K in registers ----
        float e  = s > 0.f ? s : ALPHA * s;
        float lg = adjv > 0 ? e : NEG_INF;
        float m = lg;
        #pragma unroll
        for (int off = 16; off; off >>= 1)
            m = fmaxf(m, __shfl_xor(m, off, 32));
        float p = expf(lg - m);
        float sm = p;
        #pragma unroll
        for (int off = 16; off; off >>= 1)
            sm += __shfl_xor(sm, off, 32);
        const float att = p / sm;          // lane holds att[l&31]

        // ---- phase 3: h[d] = sum_k att[k]*We[k][d]; lane owns d=l, 64+lb ----
        float ha = 0.f, hb = 0.f;
        #pragma unroll
        for (int kk = 0; kk < K; ++kk) {
            float ak = __shfl(att, kk);
            ha = fmaf(ak, we[kk * D + l], ha);
            hb = fmaf(ak, we[kk * D + 64 + lb], hb);
        }

        // ---- phase 4: out = h . WoutT + b + item via packed W4 ----
        float aa = 0.f, ab = 0.f;
        #pragma unroll
        for (int jj = 0; jj < 25; ++jj) {
            const float4 wa = W4v[jj * 100 + l];
            const float4 wb = W4v[jj * 100 + 64 + lb];
            float h0, h1, h2, h3;
            {
                const int j = 4 * jj;
                h0 = (j + 0 < 64) ? __shfl(ha, j + 0) : __shfl(hb, j - 64);
                h1 = (j + 1 < 64) ? __shfl(ha, j + 1) : __shfl(hb, j - 63);
                h2 = (j + 2 < 64) ? __shfl(ha, j + 2) : __shfl(hb, j - 62);
                h3 = (j + 3 < 64) ? __shfl(ha, j + 3) : __shfl(hb, j - 61);
            }
            aa = fmaf(h0, wa.x, aa); aa = fmaf(h1, wa.y, aa);
            aa = fmaf(h2, wa.z, aa); aa = fmaf(h3, wa.w, aa);
            ab = fmaf(h0, wb.x, ab); ab = fmaf(h1, wb.y, ab);
            ab = fmaf(h2, wb.z, ab); ab = fmaf(h3, wb.w, ab);
        }

        out[(size_t)n * D + l] = aa + bouta + itma;
        if (bl) out[(size_t)n * D + 64 + l] = ab + boutb + itmb;

        if (!more) break;
        n = n2;
        adjv = nadj; itma = nitma; itmb = nitmb;
    }
#undef LOADROW
}

extern "C" void kernel_launch(void* const* d_in, const int* in_sizes, int n_in,
                              void* d_out, int out_size, void* d_ws, size_t ws_size,
                              hipStream_t stream) {
    const float* item = (const float*)d_in[0];
    const float* ent  = (const float*)d_in[1];
    const float* wr   = (const float*)d_in[2];
    const int*   adj  = (const int*)d_in[3];
    const float* Wout = (const float*)d_in[4];
    const float* bout = (const float*)d_in[5];
    float* out = (float*)d_out;
    float* W4  = (float*)d_ws;     // 40 KB packed Wout

    const int N = 40000;
    pack_wout<<<(D * D + 255) / 256, 256, 0, stream>>>(Wout, W4);
    gat_wave_pipe<<<NBLK, 256, 0, stream>>>(item, ent, wr, adj, W4, bout, out, N);
}

// Round 6
// 222.993 us; speedup vs baseline: 4.4189x; 4.4189x over previous
//
#include <hip/hip_runtime.h>

#define NEG_INF -9e15f
#define ALPHA 0.2f

// Wave-per-row + per-wave software pipeline. Each 64-lane wave owns a row
// stream; row n+1's global loads are issued right after row n's products are
// staged to LDS, so phases 2-4 of row n hide the prefetch latency. No
// __syncthreads anywhere -> no vmcnt drain; same-wave DS ops are in-order.
// Phase 4 reads a pre-packed W4[jj][d][4] table (dwordx4, coalesced).
//
// R6 change vs R5: NO min-waves launch bound. R5's (256,3) capped VGPR at 84
// and spilled the 104-VGPR prefetch buffer to scratch (+2.7 GB HBM traffic,
// 985 us). Let the allocator use ~200 VGPRs; occupancy ~10 waves/CU.
constexpr int K = 32, D = 100, KD = K * D;     // 3200 floats, 800 float4
constexpr int NBLK = 768;                      // 3 blocks/CU (LDS-bound)
constexpr int WPB = 4;
constexpr int NSTREAM = NBLK * WPB;            // 3072 row streams

// W4[jj*400 + d*4 + c] = Wout[d][4*jj+c]  (jj<25, d<100, c<4) -> 40 KB
__global__ __launch_bounds__(256) void pack_wout(
    const float* __restrict__ W, float* __restrict__ W4)
{
    int idx = blockIdx.x * 256 + threadIdx.x;
    if (idx < D * D) {
        int jj = idx / 400;
        int r  = idx - jj * 400;
        int d  = r >> 2;
        int c  = r & 3;
        W4[idx] = W[d * D + 4 * jj + c];
    }
}

__global__ __launch_bounds__(256) void gat_wave_pipe(
    const float* __restrict__ item,   // [N, D]
    const float* __restrict__ ent,    // [N, K, D]
    const float* __restrict__ wr,     // [N, K, D]
    const int*   __restrict__ adj,    // [N, K]
    const float* __restrict__ W4,     // packed Wout in ws (40 KB)
    const float* __restrict__ bout,   // [D]
    float* __restrict__ out,          // [N, D]
    int N)
{
    __shared__ float4 sWe4[WPB * (KD / 4)];   // 51200 B, per-wave regions

    const int t   = threadIdx.x;
    const int wid = t >> 6;
    const int l   = t & 63;
    const int k   = l & 31;          // k-row this lane reduces in ksum
    const int h   = l >> 5;          // half of the k-row
    const bool bl = (l < 36);
    const int lb  = bl ? l : 35;

    float4* we4 = sWe4 + wid * (KD / 4);
    const float* we = reinterpret_cast<const float*>(we4);
    const float4* W4v = reinterpret_cast<const float4*>(W4);

    const float bouta = bout[l];
    const float boutb = bout[64 + lb];

    int n = blockIdx.x * WPB + wid;

    float4 a[12], b[12], at, bt;
    int   adjv; float itma, itmb;

#define LOADROW(NN, ADJ, ITA, ITB) do {                                        \
        const float4* e4_ = reinterpret_cast<const float4*>(ent + (size_t)(NN) * KD); \
        const float4* w4_ = reinterpret_cast<const float4*>(wr  + (size_t)(NN) * KD); \
        _Pragma("unroll")                                                      \
        for (int j = 0; j < 12; ++j) { a[j] = e4_[l + 64 * j]; b[j] = w4_[l + 64 * j]; } \
        if (l < 32) { at = e4_[768 + l]; bt = w4_[768 + l]; }                  \
        ADJ = adj[(size_t)(NN) * K + k];                                       \
        ITA = item[(size_t)(NN) * D + l];                                      \
        ITB = item[(size_t)(NN) * D + 64 + lb];                                \
    } while (0)

    LOADROW(n, adjv, itma, itmb);

    for (;;) {
        // ---- phase 1: products -> per-wave LDS (consumes a/b) ----
        #pragma unroll
        for (int j = 0; j < 12; ++j) {
            float4 p;
            p.x = a[j].x * b[j].x; p.y = a[j].y * b[j].y;
            p.z = a[j].z * b[j].z; p.w = a[j].w * b[j].w;
            we4[l + 64 * j] = p;
        }
        if (l < 32) {
            float4 p;
            p.x = at.x * bt.x; p.y = at.y * bt.y;
            p.z = at.z * bt.z; p.w = at.w * bt.w;
            we4[768 + l] = p;
        }

        // ---- issue next row's loads NOW; phases 2-4 hide the latency ----
        const int n2 = n + NSTREAM;
        const bool more = (n2 < N);
        int nadj = 0; float nitma = 0.f, nitmb = 0.f;
        if (more) LOADROW(n2, nadj, nitma, nitmb);

        // ---- ksum: lane (k,h) reads its half of k-row from LDS ----
        float s = 0.f;
        {
            const float4* base = we4 + k * 25 + (h ? 13 : 0);
            #pragma unroll
            for (int j = 0; j < 12; ++j) {
                float4 q = base[j];
                s += (q.x + q.y) + (q.z + q.w);
            }
            if (h == 0) {
                float4 q = base[12];
                s += (q.x + q.y) + (q.z + q.w);
            }
        }
        s += __shfl_xor(s, 32);

        // ---- softmax over K in registers ----
        float e  = s > 0.f ? s : ALPHA * s;
        float lg = adjv > 0 ? e : NEG_INF;
        float m = lg;
        #pragma unroll
        for (int off = 16; off; off >>= 1)
            m = fmaxf(m, __shfl_xor(m, off, 32));
        float p = expf(lg - m);
        float sm = p;
        #pragma unroll
        for (int off = 16; off; off >>= 1)
            sm += __shfl_xor(sm, off, 32);
        const float att = p / sm;          // lane holds att[l&31]

        // ---- phase 3: h[d] = sum_k att[k]*We[k][d]; lane owns d=l, 64+lb ----
        float ha = 0.f, hb = 0.f;
        #pragma unroll
        for (int kk = 0; kk < K; ++kk) {
            float ak = __shfl(att, kk);
            ha = fmaf(ak, we[kk * D + l], ha);
            hb = fmaf(ak, we[kk * D + 64 + lb], hb);
        }

        // ---- phase 4: out = h . WoutT + b + item via packed W4 ----
        float aa = 0.f, ab = 0.f;
        #pragma unroll
        for (int jj = 0; jj < 25; ++jj) {
            const float4 wa = W4v[jj * 100 + l];
            const float4 wb = W4v[jj * 100 + 64 + lb];
            float h0, h1, h2, h3;
            {
                const int j = 4 * jj;
                h0 = (j + 0 < 64) ? __shfl(ha, j + 0) : __shfl(hb, j - 64);
                h1 = (j + 1 < 64) ? __shfl(ha, j + 1) : __shfl(hb, j - 63);
                h2 = (j + 2 < 64) ? __shfl(ha, j + 2) : __shfl(hb, j - 62);
                h3 = (j + 3 < 64) ? __shfl(ha, j + 3) : __shfl(hb, j - 61);
            }
            aa = fmaf(h0, wa.x, aa); aa = fmaf(h1, wa.y, aa);
            aa = fmaf(h2, wa.z, aa); aa = fmaf(h3, wa.w, aa);
            ab = fmaf(h0, wb.x, ab); ab = fmaf(h1, wb.y, ab);
            ab = fmaf(h2, wb.z, ab); ab = fmaf(h3, wb.w, ab);
        }

        out[(size_t)n * D + l] = aa + bouta + itma;
        if (bl) out[(size_t)n * D + 64 + l] = ab + boutb + itmb;

        if (!more) break;
        n = n2;
        adjv = nadj; itma = nitma; itmb = nitmb;
    }
#undef LOADROW
}

extern "C" void kernel_launch(void* const* d_in, const int* in_sizes, int n_in,
                              void* d_out, int out_size, void* d_ws, size_t ws_size,
                              hipStream_t stream) {
    const float* item = (const float*)d_in[0];
    const float* ent  = (const float*)d_in[1];
    const float* wr   = (const float*)d_in[2];
    const int*   adj  = (const int*)d_in[3];
    const float* Wout = (const float*)d_in[4];
    const float* bout = (const float*)d_in[5];
    float* out = (float*)d_out;
    float* W4  = (float*)d_ws;     // 40 KB packed Wout

    const int N = 40000;
    pack_wout<<<(D * D + 255) / 256, 256, 0, stream>>>(Wout, W4);
    gat_wave_pipe<<<NBLK, 256, 0, stream>>>(item, ent, wr, adj, W4, bout, out, N);
}